// Round 4
// baseline (390.140 us; speedup 1.0000x reference)
//
#include <hip/hip_runtime.h>

// GCN 2-layer: out = A_hat @ relu(A_hat @ (X W1) + b1) W2 + b2
// A_hat = D^-1/2 (A+I) D^-1/2.
// R4: XCD-local CSR build. R3's scatter paid ~107 MB HBM writes (every 4 B
// nontemporal store write-through as a 64 B line; R2 equivalently via 8 XCDs
// evicting partial lines). Now edges are bucketed by x = blockIdx&7 (identical
// formula in degree+fill, so counts always match; x==hardware-XCD is only a
// locality heuristic). Each bucket's csr region is appended by one XCD with
// regular stores -> L2 merges -> ~6.4 MB full-line writebacks. A compact pass
// re-concatenates per-node segments so the proven R3 gather runs unchanged.

// ---- degree, bucketed by x = blockIdx&7 ----
__global__ void degree8_kernel(const int* __restrict__ dst, unsigned* __restrict__ deg8,
                               int n, int e) {
    int t = blockIdx.x * blockDim.x + threadIdx.x;
    if (t >= e) return;
    int x = blockIdx.x & 7;
    atomicAdd(&deg8[x * n + dst[t]], 1u);
}

// ---- scan A: exclusive scan of deg8[8n] -> rp8 (x-major segment offsets) ----
__global__ void scanA_local(const unsigned* __restrict__ deg8, unsigned* __restrict__ rp8,
                            unsigned* __restrict__ partials, int m) {
    __shared__ unsigned sh[1024];
    int i = blockIdx.x * 1024 + threadIdx.x;
    unsigned v = (i < m) ? deg8[i] : 0u;
    sh[threadIdx.x] = v;
    __syncthreads();
    for (int off = 1; off < 1024; off <<= 1) {
        unsigned t = (threadIdx.x >= (unsigned)off) ? sh[threadIdx.x - off] : 0u;
        __syncthreads();
        sh[threadIdx.x] += t;
        __syncthreads();
    }
    if (i < m) rp8[i] = sh[threadIdx.x] - v;  // exclusive
    if (threadIdx.x == 1023) partials[blockIdx.x] = sh[1023];
}

// single-block parallel scan of up to 1024 partials (serial version would be
// ~latency * m; at m=391 that's too slow)
__global__ void scan_partials_block(unsigned* __restrict__ partials, int m) {
    __shared__ unsigned sh[1024];
    unsigned v = (threadIdx.x < (unsigned)m) ? partials[threadIdx.x] : 0u;
    sh[threadIdx.x] = v;
    __syncthreads();
    for (int off = 1; off < 1024; off <<= 1) {
        unsigned t = (threadIdx.x >= (unsigned)off) ? sh[threadIdx.x - off] : 0u;
        __syncthreads();
        sh[threadIdx.x] += t;
        __syncthreads();
    }
    if (threadIdx.x < (unsigned)m) partials[threadIdx.x] = sh[threadIdx.x] - v;  // exclusive
}

__global__ void scanA_add(unsigned* __restrict__ rp8, unsigned* __restrict__ pos8,
                          const unsigned* __restrict__ partials, int m, int e) {
    int i = blockIdx.x * blockDim.x + threadIdx.x;
    if (i < m) {
        unsigned v = rp8[i] + partials[i >> 10];
        rp8[i] = v;
        pos8[i] = v;
    } else if (i == m) {
        rp8[m] = (unsigned)e;
    }
}

// ---- scan B: node-total degrees -> rp_final; dinv fused (sum is free here) ----
__global__ void scanB_local(const unsigned* __restrict__ deg8, unsigned* __restrict__ rpf,
                            unsigned* __restrict__ partials, float* __restrict__ dinv, int n) {
    __shared__ unsigned sh[1024];
    int i = blockIdx.x * 1024 + threadIdx.x;
    unsigned v = 0;
    if (i < n) {
#pragma unroll
        for (int x = 0; x < 8; ++x) v += deg8[x * n + i];
        dinv[i] = rsqrtf((float)v + 1.0f);  // +1 self-loop; always > 0
    }
    sh[threadIdx.x] = v;
    __syncthreads();
    for (int off = 1; off < 1024; off <<= 1) {
        unsigned t = (threadIdx.x >= (unsigned)off) ? sh[threadIdx.x - off] : 0u;
        __syncthreads();
        sh[threadIdx.x] += t;
        __syncthreads();
    }
    if (i < n) rpf[i] = sh[threadIdx.x] - v;  // exclusive
    if (threadIdx.x == 1023) partials[blockIdx.x] = sh[1023];
}

__global__ void scanB_add(unsigned* __restrict__ rpf, const unsigned* __restrict__ partials,
                          int n, int e) {
    int i = blockIdx.x * blockDim.x + threadIdx.x;
    if (i < n) rpf[i] += partials[i >> 10];
    else if (i == n) rpf[n] = (unsigned)e;
}

// ---- fill: XCD-local append. csr8[slot] = src | (bf16(norm) << 16) ----
// Regular store (NOT nontemporal: NT defeats L2 write-combining, R3 post-mortem).
__global__ void fill_kernel(const int* __restrict__ src, const int* __restrict__ dst,
                            const float* __restrict__ dinv, unsigned* __restrict__ pos8,
                            unsigned* __restrict__ csr8, int n, int e) {
    int t = blockIdx.x * blockDim.x + threadIdx.x;
    if (t >= e) return;
    int x = blockIdx.x & 7;  // MUST match degree8_kernel's formula
    int s = src[t], d = dst[t];
    float norm = dinv[s] * dinv[d];                                  // in (0, 1]
    unsigned nb = (__float_as_uint(norm) + 0x8000u) & 0xffff0000u;   // round-to-nearest bf16
    unsigned idx = atomicAdd(&pos8[x * n + d], 1u);
    csr8[idx] = nb | (unsigned)s;
}

// ---- compact: concatenate each node's 8 segments -> node-major csr ----
__global__ void compact_kernel(const unsigned* __restrict__ csr8, const unsigned* __restrict__ rp8,
                               const unsigned* __restrict__ rpf, unsigned* __restrict__ csr, int n) {
    int lane = threadIdx.x & 63;
    int row = blockIdx.x * 4 + (threadIdx.x >> 6);  // one wave per node
    if (row >= n) return;
    unsigned st = 0, len = 0;
    if (lane < 8) {
        st = rp8[lane * n + row];
        len = rp8[lane * n + row + 1] - st;  // valid: x-major flattened scan
    }
    unsigned base = rpf[row];
    unsigned pre = 0;
#pragma unroll
    for (int x = 0; x < 8; ++x) {
        unsigned sx = __shfl(st, x);
        unsigned lx = __shfl(len, x);
        for (unsigned k = lane; k < lx; k += 64)
            csr[base + pre + k] = csr8[sx + k];
        pre += lx;
    }
}

// ---- Y[n,64] = f(X[n,64]) @ W[64,64]; 16 lanes/row, 4 rows/wave ----
__global__ void gemm64_kernel(const float4* __restrict__ X4, const float* __restrict__ W,
                              const float* __restrict__ bias, int do_relu,
                              float4* __restrict__ Y4, int n) {
    __shared__ float4 Ws[64][16];  // Ws[k][l] = W[k][4l..4l+3]
    for (int i = threadIdx.x; i < 64 * 16; i += blockDim.x)
        Ws[i >> 4][i & 15] = ((const float4*)W)[i];
    __syncthreads();
    int lane = threadIdx.x & 63;
    int l = lane & 15;
    int gbase = lane & 48;
    int wid = blockIdx.x * (blockDim.x >> 6) + (threadIdx.x >> 6);
    int row = wid * 4 + (lane >> 4);
    if (row >= n) return;
    float4 xv = X4[(size_t)row * 16 + l];
    if (bias) {
        float4 b = ((const float4*)bias)[l];
        xv.x += b.x; xv.y += b.y; xv.z += b.z; xv.w += b.w;
    }
    if (do_relu) {
        xv.x = fmaxf(xv.x, 0.f); xv.y = fmaxf(xv.y, 0.f);
        xv.z = fmaxf(xv.z, 0.f); xv.w = fmaxf(xv.w, 0.f);
    }
    float4 acc = make_float4(0.f, 0.f, 0.f, 0.f);
#pragma unroll
    for (int k = 0; k < 64; ++k) {
        float comp = (k & 3) == 0 ? xv.x : (k & 3) == 1 ? xv.y : (k & 3) == 2 ? xv.z : xv.w;
        float a = __shfl(comp, gbase + (k >> 2));
        float4 w = Ws[k][l];
        acc.x = fmaf(a, w.x, acc.x); acc.y = fmaf(a, w.y, acc.y);
        acc.z = fmaf(a, w.z, acc.z); acc.w = fmaf(a, w.w, acc.w);
    }
    Y4[(size_t)row * 16 + l] = acc;
}

// ---- gather: 16-lane group per dst node; lane l owns cols 4l..4l+3 ----
__global__ void gather_kernel(const float4* __restrict__ xw4, const unsigned* __restrict__ csr,
                              const unsigned* __restrict__ row_ptr, const float* __restrict__ dinv,
                              const float* __restrict__ bias, float4* __restrict__ out4, int n) {
    int lane = threadIdx.x & 63;
    int l = lane & 15;
    int gbase = lane & 48;
    int wid = blockIdx.x * (blockDim.x >> 6) + (threadIdx.x >> 6);
    int row = wid * 4 + (lane >> 4);
    if (row >= n) return;  // 16-lane group exits together; shfl stays in-group
    unsigned start = row_ptr[row], end = row_ptr[row + 1];
    float di = dinv[row];
    float s2 = di * di;
    float4 acc = xw4[(size_t)row * 16 + l];  // self-loop term
    acc.x *= s2; acc.y *= s2; acc.z *= s2; acc.w *= s2;
    if (bias) {
        float4 b = ((const float4*)bias)[l];
        acc.x += b.x; acc.y += b.y; acc.z += b.z; acc.w += b.w;
    }
    for (unsigned base = start; base < end; base += 16) {
        int j = (int)(base + (unsigned)l);
        unsigned ed = (j < (int)end) ? __builtin_nontemporal_load(&csr[j]) : 0u;
        int cnt = (int)min(16u, end - base);
#pragma unroll
        for (int t = 0; t < 16; ++t) {
            unsigned p = __shfl(ed, gbase + t);
            int st = (int)(p & 0xffffu);                   // src (< 2^16: safe)
            float nrm = __uint_as_float(p & 0xffff0000u);  // bf16 -> f32 = mask
            nrm = (t < cnt) ? nrm : 0.0f;                  // predicate tail
            float4 v = xw4[(size_t)st * 16 + l];
            acc.x = fmaf(nrm, v.x, acc.x); acc.y = fmaf(nrm, v.y, acc.y);
            acc.z = fmaf(nrm, v.z, acc.z); acc.w = fmaf(nrm, v.w, acc.w);
        }
    }
    out4[(size_t)row * 16 + l] = acc;
}

extern "C" void kernel_launch(void* const* d_in, const int* in_sizes, int n_in,
                              void* d_out, int out_size, void* d_ws, size_t ws_size,
                              hipStream_t stream) {
    const float* x  = (const float*)d_in[0];
    const int*   ei = (const int*)d_in[1];
    const float* W1 = (const float*)d_in[2];
    const float* b1 = (const float*)d_in[3];
    const float* W2 = (const float*)d_in[4];
    const float* b2 = (const float*)d_in[5];
    const int n = in_sizes[0] / 64;   // 50000 (packed-csr path requires <= 65535)
    const int e = in_sizes[1] / 2;    // 1600000
    const int* src = ei;              // edge_index[0]
    const int* dst = ei + e;          // edge_index[1]

    char* ws = (char*)d_ws;
    size_t off = 0;
    auto alloc = [&](size_t bytes) -> void* {
        void* p = ws + off;
        off = (off + bytes + 255) & ~(size_t)255;
        return p;
    };
    unsigned* deg8      = (unsigned*)alloc((size_t)8 * n * 4);       // 1.6 MB
    unsigned* rp8       = (unsigned*)alloc(((size_t)8 * n + 1) * 4); // 1.6 MB
    unsigned* pos8      = (unsigned*)alloc((size_t)8 * n * 4);       // 1.6 MB
    unsigned* partialsA = (unsigned*)alloc(1024 * 4);
    unsigned* partialsB = (unsigned*)alloc(1024 * 4);
    unsigned* rpf       = (unsigned*)alloc((size_t)(n + 1) * 4);
    float*    dinv      = (float*)alloc((size_t)n * 4);
    unsigned* csr       = (unsigned*)alloc((size_t)e * 4);           // 6.4 MB node-major
    // csr8 is dead once compact finishes and gemm1 hasn't written xw yet ->
    // overlay xw on csr8 to cap ws use (~37 MB total, within proven budget).
    char*     overlay   = (char*)alloc((size_t)e * 4 > (size_t)n * 64 * 4
                                        ? (size_t)e * 4 : (size_t)n * 64 * 4);  // 12.8 MB
    unsigned* csr8      = (unsigned*)overlay;
    float*    xw        = (float*)overlay;
    float*    agg       = (float*)alloc((size_t)n * 64 * 4);         // 12.8 MB
    float*    outf      = (float*)d_out;

    const int mA = 8 * n;                    // 400000
    const int nbA = (mA + 1023) / 1024;      // 391
    const int nbB = (n + 1023) / 1024;       // 49

    // CSR build (shared by both layers)
    hipMemsetAsync(deg8, 0, (size_t)mA * 4, stream);
    degree8_kernel<<<(e + 255) / 256, 256, 0, stream>>>(dst, deg8, n, e);
    scanA_local<<<nbA, 1024, 0, stream>>>(deg8, rp8, partialsA, mA);
    scan_partials_block<<<1, 1024, 0, stream>>>(partialsA, nbA);
    scanA_add<<<(mA + 1 + 255) / 256, 256, 0, stream>>>(rp8, pos8, partialsA, mA, e);
    scanB_local<<<nbB, 1024, 0, stream>>>(deg8, rpf, partialsB, dinv, n);
    scan_partials_block<<<1, 1024, 0, stream>>>(partialsB, nbB);
    scanB_add<<<(n + 1 + 255) / 256, 256, 0, stream>>>(rpf, partialsB, n, e);
    fill_kernel<<<(e + 255) / 256, 256, 0, stream>>>(src, dst, dinv, pos8, csr8, n, e);
    compact_kernel<<<(n + 3) / 4, 256, 0, stream>>>(csr8, rp8, rpf, csr, n);

    // layer 1: xw = x @ W1 ; agg = A_hat-gather(xw)   (xw overwrites dead csr8)
    gemm64_kernel<<<(n + 15) / 16, 256, 0, stream>>>((const float4*)x, W1, nullptr, 0, (float4*)xw, n);
    gather_kernel<<<(n + 15) / 16, 256, 0, stream>>>((const float4*)xw, csr, rpf, dinv, nullptr, (float4*)agg, n);

    // layer 2: xw = relu(agg + b1) @ W2 ; out = A_hat-gather(xw) + b2
    gemm64_kernel<<<(n + 15) / 16, 256, 0, stream>>>((const float4*)agg, W2, b1, 1, (float4*)xw, n);
    gather_kernel<<<(n + 15) / 16, 256, 0, stream>>>((const float4*)xw, csr, rpf, dinv, b2, (float4*)outf, n);
}

// Round 5
// 351.529 us; speedup vs baseline: 1.1098x; 1.1098x over previous
//
#include <hip/hip_runtime.h>
#include <hip/hip_fp16.h>

// GCN 2-layer: out = A_hat @ relu(A_hat @ (X W1) + b1) W2 + b2
// A_hat = D^-1/2 (A+I) D^-1/2.
// R5: (1) xw stored fp16 -> gather's random 256 B row reads become 128 B
//     (410->205 MB LLC traffic per layer; fp16 2^-11 error << bf16-norm 2^-8).
//     (2) degree/fill: 4 edges/thread via int4 NT loads (ILP on the
//     load->atomic->store latency chain; NT so the edge stream doesn't evict
//     partially-filled csr8 lines from the XCD-local L2 — R4's residual 62 MB).
//     Bucket = blockIdx&7 at 1024-edge granularity, identical in both kernels.
//     (3) merged partials-scan + merged scan-add (2 fewer launches).

typedef int   int4v   __attribute__((ext_vector_type(4)));

// ---- degree, bucketed by x = blockIdx&7 (1024 edges per block) ----
__global__ void degree8_kernel(const int* __restrict__ dst, unsigned* __restrict__ deg8,
                               int n, int e) {
    int b = blockIdx.x;
    int i = b * 256 + threadIdx.x;   // int4 index
    int t = i * 4;
    int x = b & 7;
    if (t + 3 < e) {
        int4v d4 = __builtin_nontemporal_load((const int4v*)dst + i);
#pragma unroll
        for (int k = 0; k < 4; ++k) atomicAdd(&deg8[x * n + d4[k]], 1u);
    } else {
        for (int k = 0; k < 4; ++k)
            if (t + k < e) atomicAdd(&deg8[x * n + dst[t + k]], 1u);
    }
}

// ---- block scans ----
__global__ void scanA_local(const unsigned* __restrict__ deg8, unsigned* __restrict__ rp8,
                            unsigned* __restrict__ partials, int m) {
    __shared__ unsigned sh[1024];
    int i = blockIdx.x * 1024 + threadIdx.x;
    unsigned v = (i < m) ? deg8[i] : 0u;
    sh[threadIdx.x] = v;
    __syncthreads();
    for (int off = 1; off < 1024; off <<= 1) {
        unsigned t = (threadIdx.x >= (unsigned)off) ? sh[threadIdx.x - off] : 0u;
        __syncthreads();
        sh[threadIdx.x] += t;
        __syncthreads();
    }
    if (i < m) rp8[i] = sh[threadIdx.x] - v;  // exclusive
    if (threadIdx.x == 1023) partials[blockIdx.x] = sh[1023];
}

// node-total degrees -> rpf (pre-add); dinv fused
__global__ void scanB_local(const unsigned* __restrict__ deg8, unsigned* __restrict__ rpf,
                            unsigned* __restrict__ partials, float* __restrict__ dinv, int n) {
    __shared__ unsigned sh[1024];
    int i = blockIdx.x * 1024 + threadIdx.x;
    unsigned v = 0;
    if (i < n) {
#pragma unroll
        for (int x = 0; x < 8; ++x) v += deg8[x * n + i];
        dinv[i] = rsqrtf((float)v + 1.0f);  // +1 self-loop; always > 0
    }
    sh[threadIdx.x] = v;
    __syncthreads();
    for (int off = 1; off < 1024; off <<= 1) {
        unsigned t = (threadIdx.x >= (unsigned)off) ? sh[threadIdx.x - off] : 0u;
        __syncthreads();
        sh[threadIdx.x] += t;
        __syncthreads();
    }
    if (i < n) rpf[i] = sh[threadIdx.x] - v;  // exclusive
    if (threadIdx.x == 1023) partials[blockIdx.x] = sh[1023];
}

// block 0 scans partialsA[mA_], block 1 scans partialsB[mB_] (both <= 1024)
__global__ void scan_partials_both(unsigned* __restrict__ pA, int mA_,
                                   unsigned* __restrict__ pB, int mB_) {
    __shared__ unsigned sh[1024];
    unsigned* p = blockIdx.x ? pB : pA;
    int m = blockIdx.x ? mB_ : mA_;
    unsigned v = (threadIdx.x < (unsigned)m) ? p[threadIdx.x] : 0u;
    sh[threadIdx.x] = v;
    __syncthreads();
    for (int off = 1; off < 1024; off <<= 1) {
        unsigned t = (threadIdx.x >= (unsigned)off) ? sh[threadIdx.x - off] : 0u;
        __syncthreads();
        sh[threadIdx.x] += t;
        __syncthreads();
    }
    if (threadIdx.x < (unsigned)m) p[threadIdx.x] = sh[threadIdx.x] - v;  // exclusive
}

// A-part: rp8/pos8 over [0, mA]; B-part: rpf over [0, n]. One launch.
__global__ void scan_add_kernel(unsigned* __restrict__ rp8, unsigned* __restrict__ pos8,
                                const unsigned* __restrict__ pA, unsigned* __restrict__ rpf,
                                const unsigned* __restrict__ pB, int mA, int n, int e) {
    int i = blockIdx.x * blockDim.x + threadIdx.x;
    if (i < mA) {
        unsigned v = rp8[i] + pA[i >> 10];
        rp8[i] = v;
        pos8[i] = v;
    } else if (i == mA) {
        rp8[mA] = (unsigned)e;
    }
    int j = i - (mA + 1);
    if (j >= 0) {
        if (j < n) rpf[j] += pB[j >> 10];
        else if (j == n) rpf[n] = (unsigned)e;
    }
}

// ---- fill: XCD-local append, 4 edges/thread. csr8[slot] = src | bf16(norm)<<16 ----
__global__ void fill_kernel(const int* __restrict__ src, const int* __restrict__ dst,
                            const float* __restrict__ dinv, unsigned* __restrict__ pos8,
                            unsigned* __restrict__ csr8, int n, int e) {
    int b = blockIdx.x;
    int i = b * 256 + threadIdx.x;   // int4 index
    int t = i * 4;
    int x = b & 7;  // MUST match degree8_kernel's bucketing (1024-edge blocks)
    if (t + 3 < e) {
        int4v s4 = __builtin_nontemporal_load((const int4v*)src + i);
        int4v d4 = __builtin_nontemporal_load((const int4v*)dst + i);
        float ds0 = dinv[s4[0]], ds1 = dinv[s4[1]], ds2 = dinv[s4[2]], ds3 = dinv[s4[3]];
        float dd0 = dinv[d4[0]], dd1 = dinv[d4[1]], dd2 = dinv[d4[2]], dd3 = dinv[d4[3]];
        unsigned n0 = (__float_as_uint(ds0 * dd0) + 0x8000u) & 0xffff0000u;
        unsigned n1 = (__float_as_uint(ds1 * dd1) + 0x8000u) & 0xffff0000u;
        unsigned n2 = (__float_as_uint(ds2 * dd2) + 0x8000u) & 0xffff0000u;
        unsigned n3 = (__float_as_uint(ds3 * dd3) + 0x8000u) & 0xffff0000u;
        unsigned i0 = atomicAdd(&pos8[x * n + d4[0]], 1u);
        unsigned i1 = atomicAdd(&pos8[x * n + d4[1]], 1u);
        unsigned i2 = atomicAdd(&pos8[x * n + d4[2]], 1u);
        unsigned i3 = atomicAdd(&pos8[x * n + d4[3]], 1u);
        csr8[i0] = n0 | (unsigned)s4[0];
        csr8[i1] = n1 | (unsigned)s4[1];
        csr8[i2] = n2 | (unsigned)s4[2];
        csr8[i3] = n3 | (unsigned)s4[3];
    } else {
        for (int k = 0; k < 4; ++k) {
            if (t + k >= e) break;
            int s = src[t + k], d = dst[t + k];
            unsigned nb = (__float_as_uint(dinv[s] * dinv[d]) + 0x8000u) & 0xffff0000u;
            unsigned idx = atomicAdd(&pos8[x * n + d], 1u);
            csr8[idx] = nb | (unsigned)s;
        }
    }
}

// ---- compact: concatenate each node's 8 segments -> node-major csr ----
__global__ void compact_kernel(const unsigned* __restrict__ csr8, const unsigned* __restrict__ rp8,
                               const unsigned* __restrict__ rpf, unsigned* __restrict__ csr, int n) {
    int lane = threadIdx.x & 63;
    int row = blockIdx.x * 4 + (threadIdx.x >> 6);  // one wave per node
    if (row >= n) return;
    unsigned st = 0, len = 0;
    if (lane < 8) {
        st = rp8[lane * n + row];
        len = rp8[lane * n + row + 1] - st;  // valid in flattened x-major scan
    }
    unsigned base = rpf[row];
    unsigned pre = 0;
#pragma unroll
    for (int x = 0; x < 8; ++x) {
        unsigned sx = __shfl(st, x);
        unsigned lx = __shfl(len, x);
        for (unsigned k = lane; k < lx; k += 64)
            csr[base + pre + k] = csr8[sx + k];
        pre += lx;
    }
}

// ---- Yh[n,64] (fp16) = f(X[n,64]) @ W[64,64]; 16 lanes/row, 4 rows/wave ----
__global__ void gemm64_kernel(const float4* __restrict__ X4, const float* __restrict__ W,
                              const float* __restrict__ bias, int do_relu,
                              __half* __restrict__ Yh, int n) {
    __shared__ float4 Ws[64][16];  // Ws[k][l] = W[k][4l..4l+3]
    for (int i = threadIdx.x; i < 64 * 16; i += blockDim.x)
        Ws[i >> 4][i & 15] = ((const float4*)W)[i];
    __syncthreads();
    int lane = threadIdx.x & 63;
    int l = lane & 15;
    int gbase = lane & 48;
    int wid = blockIdx.x * (blockDim.x >> 6) + (threadIdx.x >> 6);
    int row = wid * 4 + (lane >> 4);
    if (row >= n) return;
    float4 xv = X4[(size_t)row * 16 + l];
    if (bias) {
        float4 b = ((const float4*)bias)[l];
        xv.x += b.x; xv.y += b.y; xv.z += b.z; xv.w += b.w;
    }
    if (do_relu) {
        xv.x = fmaxf(xv.x, 0.f); xv.y = fmaxf(xv.y, 0.f);
        xv.z = fmaxf(xv.z, 0.f); xv.w = fmaxf(xv.w, 0.f);
    }
    float4 acc = make_float4(0.f, 0.f, 0.f, 0.f);
#pragma unroll
    for (int k = 0; k < 64; ++k) {
        float comp = (k & 3) == 0 ? xv.x : (k & 3) == 1 ? xv.y : (k & 3) == 2 ? xv.z : xv.w;
        float a = __shfl(comp, gbase + (k >> 2));
        float4 w = Ws[k][l];
        acc.x = fmaf(a, w.x, acc.x); acc.y = fmaf(a, w.y, acc.y);
        acc.z = fmaf(a, w.z, acc.z); acc.w = fmaf(a, w.w, acc.w);
    }
    __half2 h0 = __floats2half2_rn(acc.x, acc.y);
    __half2 h1 = __floats2half2_rn(acc.z, acc.w);
    uint2 o;
    o.x = *(const unsigned*)&h0;
    o.y = *(const unsigned*)&h1;
    *(uint2*)(Yh + (size_t)row * 64 + 4 * l) = o;
}

// ---- gather: 16-lane group per dst node; lane l owns cols 4l..4l+3 (fp16 xw) ----
__global__ void gather_kernel(const __half* __restrict__ xwh, const unsigned* __restrict__ csr,
                              const unsigned* __restrict__ row_ptr, const float* __restrict__ dinv,
                              const float* __restrict__ bias, float4* __restrict__ out4, int n) {
    int lane = threadIdx.x & 63;
    int l = lane & 15;
    int gbase = lane & 48;
    int wid = blockIdx.x * (blockDim.x >> 6) + (threadIdx.x >> 6);
    int row = wid * 4 + (lane >> 4);
    if (row >= n) return;  // 16-lane group exits together; shfl stays in-group
    unsigned start = row_ptr[row], end = row_ptr[row + 1];
    float di = dinv[row];
    float s2 = di * di;
    float4 acc;
    {   // self-loop term
        uint2 hv = *(const uint2*)(xwh + (size_t)row * 64 + 4 * l);
        float2 f0 = __half22float2(*(const __half2*)&hv.x);
        float2 f1 = __half22float2(*(const __half2*)&hv.y);
        acc = make_float4(f0.x * s2, f0.y * s2, f1.x * s2, f1.y * s2);
    }
    if (bias) {
        float4 b = ((const float4*)bias)[l];
        acc.x += b.x; acc.y += b.y; acc.z += b.z; acc.w += b.w;
    }
    for (unsigned base = start; base < end; base += 16) {
        int j = (int)(base + (unsigned)l);
        unsigned ed = (j < (int)end) ? __builtin_nontemporal_load(&csr[j]) : 0u;
        int cnt = (int)min(16u, end - base);
#pragma unroll
        for (int t = 0; t < 16; ++t) {
            unsigned p = __shfl(ed, gbase + t);
            int st = (int)(p & 0xffffu);                   // src (< 2^16: safe)
            float nrm = __uint_as_float(p & 0xffff0000u);  // bf16 -> f32 = mask
            nrm = (t < cnt) ? nrm : 0.0f;                  // predicate tail
            uint2 hv = *(const uint2*)(xwh + (size_t)st * 64 + 4 * l);
            float2 f0 = __half22float2(*(const __half2*)&hv.x);
            float2 f1 = __half22float2(*(const __half2*)&hv.y);
            acc.x = fmaf(nrm, f0.x, acc.x); acc.y = fmaf(nrm, f0.y, acc.y);
            acc.z = fmaf(nrm, f1.x, acc.z); acc.w = fmaf(nrm, f1.y, acc.w);
        }
    }
    out4[(size_t)row * 16 + l] = acc;
}

extern "C" void kernel_launch(void* const* d_in, const int* in_sizes, int n_in,
                              void* d_out, int out_size, void* d_ws, size_t ws_size,
                              hipStream_t stream) {
    const float* x  = (const float*)d_in[0];
    const int*   ei = (const int*)d_in[1];
    const float* W1 = (const float*)d_in[2];
    const float* b1 = (const float*)d_in[3];
    const float* W2 = (const float*)d_in[4];
    const float* b2 = (const float*)d_in[5];
    const int n = in_sizes[0] / 64;   // 50000 (packed-csr path requires <= 65535)
    const int e = in_sizes[1] / 2;    // 1600000
    const int* src = ei;              // edge_index[0]
    const int* dst = ei + e;          // edge_index[1]

    char* ws = (char*)d_ws;
    size_t off = 0;
    auto alloc = [&](size_t bytes) -> void* {
        void* p = ws + off;
        off = (off + bytes + 255) & ~(size_t)255;
        return p;
    };
    unsigned* deg8      = (unsigned*)alloc((size_t)8 * n * 4);       // 1.6 MB
    unsigned* rp8       = (unsigned*)alloc(((size_t)8 * n + 1) * 4); // 1.6 MB
    unsigned* pos8      = (unsigned*)alloc((size_t)8 * n * 4);       // 1.6 MB
    unsigned* partialsA = (unsigned*)alloc(1024 * 4);
    unsigned* partialsB = (unsigned*)alloc(1024 * 4);
    unsigned* rpf       = (unsigned*)alloc((size_t)(n + 1) * 4);
    float*    dinv      = (float*)alloc((size_t)n * 4);
    unsigned* csr       = (unsigned*)alloc((size_t)e * 4);           // 6.4 MB node-major
    // csr8 dead after compact; xwh (fp16, 6.4 MB) overlays it.
    size_t ov = (size_t)e * 4 > (size_t)n * 64 * 2 ? (size_t)e * 4 : (size_t)n * 64 * 2;
    char*     overlay   = (char*)alloc(ov);
    unsigned* csr8      = (unsigned*)overlay;
    __half*   xwh       = (__half*)overlay;
    float*    agg       = (float*)alloc((size_t)n * 64 * 4);         // 12.8 MB
    float*    outf      = (float*)d_out;

    const int mA = 8 * n;                    // 400000
    const int nbA = (mA + 1023) / 1024;      // 391
    const int nbB = (n + 1023) / 1024;       // 49
    const int nbE = (e + 1023) / 1024;       // 1563 (1024 edges per block)

    // CSR build (shared by both layers)
    hipMemsetAsync(deg8, 0, (size_t)mA * 4, stream);
    degree8_kernel<<<nbE, 256, 0, stream>>>(dst, deg8, n, e);
    scanA_local<<<nbA, 1024, 0, stream>>>(deg8, rp8, partialsA, mA);
    scanB_local<<<nbB, 1024, 0, stream>>>(deg8, rpf, partialsB, dinv, n);
    scan_partials_both<<<2, 1024, 0, stream>>>(partialsA, nbA, partialsB, nbB);
    scan_add_kernel<<<(mA + n + 2 + 255) / 256, 256, 0, stream>>>(rp8, pos8, partialsA,
                                                                  rpf, partialsB, mA, n, e);
    fill_kernel<<<nbE, 256, 0, stream>>>(src, dst, dinv, pos8, csr8, n, e);
    compact_kernel<<<(n + 3) / 4, 256, 0, stream>>>(csr8, rp8, rpf, csr, n);

    // layer 1: xwh = fp16(x @ W1) ; agg = A_hat-gather(xwh)   (xwh overwrites dead csr8)
    gemm64_kernel<<<(n + 15) / 16, 256, 0, stream>>>((const float4*)x, W1, nullptr, 0, xwh, n);
    gather_kernel<<<(n + 15) / 16, 256, 0, stream>>>(xwh, csr, rpf, dinv, nullptr, (float4*)agg, n);

    // layer 2: xwh = fp16(relu(agg + b1) @ W2) ; out = A_hat-gather(xwh) + b2
    gemm64_kernel<<<(n + 15) / 16, 256, 0, stream>>>((const float4*)agg, W2, b1, 1, xwh, n);
    gather_kernel<<<(n + 15) / 16, 256, 0, stream>>>(xwh, csr, rpf, dinv, b2, (float4*)outf, n);
}